// Round 1
// baseline (147.887 us; speedup 1.0000x reference)
//
#include <hip/hip_runtime.h>

#define DEV __device__ __forceinline__

DEV float shflx(float v, int m) { return __shfl_xor(v, m, 64); }

// RZ(bit): diagonal phase; amp(bit=0) *= (c - i s), amp(bit=1) *= (c + i s)
DEV void gate_rz(float re[4], float im[4], int lane, int bt, float c, float s) {
#pragma unroll
  for (int r = 0; r < 4; ++r) {
    int idx = (lane << 2) | r;
    float t = ((idx >> bt) & 1) ? -s : s;
    float nr = fmaf(c, re[r],  t * im[r]);
    float ni = fmaf(c, im[r], -t * re[r]);
    re[r] = nr; im[r] = ni;
  }
}

// real 2x2 [[m00,m01],[m10,m11]] on target bit bt, controlled on bit bc (bc<0 = uncontrolled)
DEV void gate_real(float re[4], float im[4], int lane, int bt, int bc,
                   float m00, float m01, float m10, float m11) {
  if (bt >= 2) {
    int sh = bt - 2, d = 1 << sh;
    int side = (lane >> sh) & 1;
    float cme = side ? m11 : m00;   // coeff on my element
    float cp  = side ? m10 : m01;   // coeff on partner element
#pragma unroll
    for (int r = 0; r < 4; ++r) {
      float pr = shflx(re[r], d), pi = shflx(im[r], d);
      float nr = fmaf(cme, re[r], cp * pr);
      float ni = fmaf(cme, im[r], cp * pi);
      int idx = (lane << 2) | r;
      bool cb = (bc < 0) || (((idx >> bc) & 1) != 0);
      re[r] = cb ? nr : re[r];
      im[r] = cb ? ni : im[r];
    }
  } else {
#define PAIR_REAL(I, J) { \
      bool cb = (bc < 0) || (((((lane << 2) | (I)) >> bc) & 1) != 0); \
      float ar = re[I], ai = im[I], br = re[J], bi = im[J]; \
      float n0r = fmaf(m00, ar, m01 * br), n0i = fmaf(m00, ai, m01 * bi); \
      float n1r = fmaf(m10, ar, m11 * br), n1i = fmaf(m10, ai, m11 * bi); \
      re[I] = cb ? n0r : ar; im[I] = cb ? n0i : ai; \
      re[J] = cb ? n1r : br; im[J] = cb ? n1i : bi; }
    if (bt == 1) { PAIR_REAL(0, 2); PAIR_REAL(1, 3); }
    else         { PAIR_REAL(0, 1); PAIR_REAL(2, 3); }
#undef PAIR_REAL
  }
}

// controlled RX on target bit bt, control bit bc.
// Both sides reduce to: new_re = c*me_re + s*p_im ; new_im = c*me_im - s*p_re
DEV void gate_crx(float re[4], float im[4], int lane, int bt, int bc, float c, float s) {
  if (bt >= 2) {
    int sh = bt - 2, d = 1 << sh;
#pragma unroll
    for (int r = 0; r < 4; ++r) {
      float pr = shflx(re[r], d), pi = shflx(im[r], d);
      float nr = fmaf(c, re[r],  s * pi);
      float ni = fmaf(c, im[r], -s * pr);
      int idx = (lane << 2) | r;
      bool cb = ((idx >> bc) & 1) != 0;
      re[r] = cb ? nr : re[r];
      im[r] = cb ? ni : im[r];
    }
  } else {
#define PAIR_CRX(I, J) { \
      bool cb = (((((lane << 2) | (I)) >> bc) & 1) != 0); \
      float n0r = fmaf(c, re[I],  s * im[J]), n0i = fmaf(c, im[I], -s * re[J]); \
      float n1r = fmaf(c, re[J],  s * im[I]), n1i = fmaf(c, im[J], -s * re[I]); \
      re[I] = cb ? n0r : re[I]; im[I] = cb ? n0i : im[I]; \
      re[J] = cb ? n1r : re[J]; im[J] = cb ? n1i : im[J]; }
    if (bt == 1) { PAIR_CRX(0, 2); PAIR_CRX(1, 3); }
    else         { PAIR_CRX(0, 1); PAIR_CRX(2, 3); }
#undef PAIR_CRX
  }
}

// One wave (64 lanes) simulates one batch element. 256 amplitudes,
// amp index = (lane<<2)|r : bits 0,1 in-lane, bits 2..7 = lane bits 0..5.
__global__ __launch_bounds__(256) void qsim_kernel(const float* __restrict__ X,
                                                   const float* __restrict__ W,
                                                   float* __restrict__ out, int bs) {
  const int lane = threadIdx.x & 63;
  const int b = blockIdx.x * (blockDim.x >> 6) + (threadIdx.x >> 6);
  if (b >= bs) return;

  // Precompute all 64 rotation sincos across the wave (lane l holds angle X[b,l]).
  float xl = X[(size_t)b * 64 + lane];
  float shh, ch;
  __sincosf(0.5f * xl, &shh, &ch);

  // Weight sincos in lanes 0..15: gate g -> weights[(g>>3)*16 + (g&7)]
  float cw = 0.f, sw = 0.f;
  if (lane < 16) {
    float w = W[((lane >> 3) << 4) + (lane & 7)];
    __sincosf(0.5f * w, &sw, &cw);
  }

  // |0...0>
  float re[4] = {0.f, 0.f, 0.f, 0.f}, im[4] = {0.f, 0.f, 0.f, 0.f};
  if (lane == 0) re[0] = 1.f;

  const float Hc = 0.70710678118654752440f;

  // Encoding block: per qubit q (bit 7-q): H then RZ/RY alternation, vpq=9 (q=7: 1)
  for (int q = 0; q < 8; ++q) {
    int bt = 7 - q;
    gate_real(re, im, lane, bt, -1, Hc, Hc, Hc, -Hc);
    int nrot = (q == 7) ? 1 : 9;
    for (int i = 0; i < nrot; ++i) {
      int idx = q * 9 + i;
      float c = __shfl(ch, idx, 64);
      float s = __shfl(shh, idx, 64);
      if (i & 1) gate_real(re, im, lane, bt, -1, c, -s, s, c);  // RY
      else       gate_rz(re, im, lane, bt, c, s);               // RZ
    }
  }

  // Entangling: layer 0 = CRX, layer 1 = CRY; control=i, target=(i+1)%8
  for (int g = 0; g < 16; ++g) {
    int l = g >> 3, i = g & 7;
    float c = __shfl(cw, g, 64);
    float s = __shfl(sw, g, 64);
    int bc = 7 - i;
    int bt = 7 - ((i + 1) & 7);
    if (l == 0) gate_crx(re, im, lane, bt, bc, c, s);
    else        gate_real(re, im, lane, bt, bc, c, -s, s, c);   // CRY
  }

  // Measurement: <Z_q> = sum p*(+1 if bit(7-q)==0 else -1)
  float p[4];
#pragma unroll
  for (int r = 0; r < 4; ++r) p[r] = fmaf(re[r], re[r], im[r] * im[r]);

  float v[8];
#pragma unroll
  for (int q = 0; q < 8; ++q) {
    int bp = 7 - q;
    float acc = 0.f;
#pragma unroll
    for (int r = 0; r < 4; ++r) {
      int idx = (lane << 2) | r;
      acc += ((idx >> bp) & 1) ? -p[r] : p[r];
    }
    v[q] = acc;
  }
#pragma unroll
  for (int d = 1; d < 64; d <<= 1) {
#pragma unroll
    for (int q = 0; q < 8; ++q) v[q] += shflx(v[q], d);
  }
  float o = v[0];
#pragma unroll
  for (int q = 1; q < 8; ++q) if (lane == q) o = v[q];
  if (lane < 8) out[(size_t)b * 8 + lane] = o;
}

extern "C" void kernel_launch(void* const* d_in, const int* in_sizes, int n_in,
                              void* d_out, int out_size, void* d_ws, size_t ws_size,
                              hipStream_t stream) {
  const float* X = (const float*)d_in[0];   // (bs, 64) float32
  const float* W = (const float*)d_in[1];   // (2, 16) float32
  float* out = (float*)d_out;               // (bs, 8) float32
  int bs = in_sizes[0] / 64;
  const int waves_per_block = 4;
  const int threads = waves_per_block * 64;
  int blocks = (bs + waves_per_block - 1) / waves_per_block;
  hipLaunchKernelGGL(qsim_kernel, dim3(blocks), dim3(threads), 0, stream, X, W, out, bs);
}

// Round 2
// 94.993 us; speedup vs baseline: 1.5568x; 1.5568x over previous
//
#include <hip/hip_runtime.h>

#define DEV __device__ __forceinline__

DEV float shflx(float v, int m) { return __shfl_xor(v, m, 64); }
// VALU broadcast (v_readlane_b32 -> SGPR), no DS pipe.
DEV float rdlane(float v, int l) {
  return __int_as_float(__builtin_amdgcn_readlane(__float_as_int(v), l));
}

// Apply SU(2) gate M = [[a, -b*],[b, a*]] (a=ar+i*ai, b=br+i*bi) on target bit bt.
// Amp index = (lane<<2)|r : bits 0,1 in-lane, bits 2..7 = lane bits 0..5.
DEV void apply_su2(float re[4], float im[4], int lane, int bt,
                   float ar, float ai, float br, float bi) {
  if (bt >= 2) {
    const int sh = bt - 2, d = 1 << sh;
    const int side = (lane >> sh) & 1;
    // side0: new = a*me + (-b*)*p ; side1: new = a**me + b*p
    const float aim = side ? -ai : ai;
    const float brs = side ? br : -br;
#pragma unroll
    for (int r = 0; r < 4; ++r) {
      float pr = shflx(re[r], d), pi = shflx(im[r], d);
      float mr = re[r], mi = im[r];
      re[r] = ar * mr - aim * mi + brs * pr - bi * pi;
      im[r] = ar * mi + aim * mr + brs * pi + bi * pr;
    }
  } else {
#define PAIR_SU2(I, J) { \
      float rI = re[I], iI = im[I], rJ = re[J], iJ = im[J]; \
      re[I] = ar * rI - ai * iI - br * rJ - bi * iJ; \
      im[I] = ar * iI + ai * rI - br * iJ + bi * rJ; \
      re[J] = br * rI - bi * iI + ar * rJ + ai * iJ; \
      im[J] = br * iI + bi * rI + ar * iJ - ai * rJ; }
    if (bt == 1) { PAIR_SU2(0, 2); PAIR_SU2(1, 3); }
    else         { PAIR_SU2(0, 1); PAIR_SU2(2, 3); }
#undef PAIR_SU2
  }
}

// real 2x2 [[m00,m01],[m10,m11]] on target bit bt, controlled on bit bc
DEV void gate_real(float re[4], float im[4], int lane, int bt, int bc,
                   float m00, float m01, float m10, float m11) {
  if (bt >= 2) {
    int sh = bt - 2, d = 1 << sh;
    int side = (lane >> sh) & 1;
    float cme = side ? m11 : m00;
    float cp  = side ? m10 : m01;
#pragma unroll
    for (int r = 0; r < 4; ++r) {
      float pr = shflx(re[r], d), pi = shflx(im[r], d);
      float nr = fmaf(cme, re[r], cp * pr);
      float ni = fmaf(cme, im[r], cp * pi);
      int idx = (lane << 2) | r;
      bool cb = (bc < 0) || (((idx >> bc) & 1) != 0);
      re[r] = cb ? nr : re[r];
      im[r] = cb ? ni : im[r];
    }
  } else {
#define PAIR_REAL(I, J) { \
      bool cb = (bc < 0) || (((((lane << 2) | (I)) >> bc) & 1) != 0); \
      float ar_ = re[I], ai_ = im[I], br_ = re[J], bi_ = im[J]; \
      float n0r = fmaf(m00, ar_, m01 * br_), n0i = fmaf(m00, ai_, m01 * bi_); \
      float n1r = fmaf(m10, ar_, m11 * br_), n1i = fmaf(m10, ai_, m11 * bi_); \
      re[I] = cb ? n0r : ar_; im[I] = cb ? n0i : ai_; \
      re[J] = cb ? n1r : br_; im[J] = cb ? n1i : bi_; }
    if (bt == 1) { PAIR_REAL(0, 2); PAIR_REAL(1, 3); }
    else         { PAIR_REAL(0, 1); PAIR_REAL(2, 3); }
#undef PAIR_REAL
  }
}

// controlled RX on target bit bt, control bit bc
DEV void gate_crx(float re[4], float im[4], int lane, int bt, int bc, float c, float s) {
  if (bt >= 2) {
    int sh = bt - 2, d = 1 << sh;
#pragma unroll
    for (int r = 0; r < 4; ++r) {
      float pr = shflx(re[r], d), pi = shflx(im[r], d);
      float nr = fmaf(c, re[r],  s * pi);
      float ni = fmaf(c, im[r], -s * pr);
      int idx = (lane << 2) | r;
      bool cb = ((idx >> bc) & 1) != 0;
      re[r] = cb ? nr : re[r];
      im[r] = cb ? ni : im[r];
    }
  } else {
#define PAIR_CRX(I, J) { \
      bool cb = (((((lane << 2) | (I)) >> bc) & 1) != 0); \
      float n0r = fmaf(c, re[I],  s * im[J]), n0i = fmaf(c, im[I], -s * re[J]); \
      float n1r = fmaf(c, re[J],  s * im[I]), n1i = fmaf(c, im[J], -s * re[I]); \
      re[I] = cb ? n0r : re[I]; im[I] = cb ? n0i : im[I]; \
      re[J] = cb ? n1r : re[J]; im[J] = cb ? n1i : im[J]; }
    if (bt == 1) { PAIR_CRX(0, 2); PAIR_CRX(1, 3); }
    else         { PAIR_CRX(0, 1); PAIR_CRX(2, 3); }
#undef PAIR_CRX
  }
}

// One wave per batch element; 256 amplitudes, 4 complex per lane.
__global__ __launch_bounds__(256) void qsim_kernel(const float* __restrict__ X,
                                                   const float* __restrict__ W,
                                                   float* __restrict__ out, int bs) {
  const int lane = threadIdx.x & 63;
  const int b = blockIdx.x * (blockDim.x >> 6) + (threadIdx.x >> 6);
  if (b >= bs) return;

  // lane l holds sincos of encoding angle l
  float xl = X[(size_t)b * 64 + lane];
  float shh, ch;
  __sincosf(0.5f * xl, &shh, &ch);

  // lane l (all lanes, mod 16) holds sincos of entangling weight (l&15)
  float w = W[(((lane & 15) >> 3) << 4) + (lane & 7)];
  float sw, cw;
  __sincosf(0.5f * w, &sw, &cw);

  float re[4] = {0.f, 0.f, 0.f, 0.f}, im[4] = {0.f, 0.f, 0.f, 0.f};
  if (lane == 0) re[0] = 1.f;

  const float Hc = 0.70710678118654752440f;

  // Encoding: per qubit q, fuse (R_{n-1}...R_0 · (-i)H) into one SU(2) (a,b).
  // (-i)H is SU(2): a = -i*Hc, b = -i*Hc. Global phase cancels in |amp|^2.
#pragma unroll
  for (int q = 0; q < 8; ++q) {
    float ar = 0.f, ai = -Hc, br = 0.f, bi = -Hc;
    const int nrot = (q == 7) ? 1 : 9;
#pragma unroll
    for (int i = 0; i < nrot; ++i) {
      float c = rdlane(ch,  q * 9 + i);
      float s = rdlane(shh, q * 9 + i);
      if ((i & 1) == 0) { // RZ: a *= (c - i s), b *= (c + i s)
        float nar = ar * c + ai * s, nai = ai * c - ar * s;
        float nbr = br * c - bi * s, nbi = bi * c + br * s;
        ar = nar; ai = nai; br = nbr; bi = nbi;
      } else {            // RY: a' = c a - s b ; b' = s a + c b
        float nar = c * ar - s * br, nai = c * ai - s * bi;
        float nbr = s * ar + c * br, nbi = s * ai + c * bi;
        ar = nar; ai = nai; br = nbr; bi = nbi;
      }
    }
    apply_su2(re, im, lane, 7 - q, ar, ai, br, bi);
  }

  // Entangling: layer 0 = CRX, layer 1 = CRY; control=i, target=(i+1)%8
#pragma unroll
  for (int g = 0; g < 16; ++g) {
    const int l = g >> 3, i = g & 7;
    float c = rdlane(cw, g);
    float s = rdlane(sw, g);
    const int bc = 7 - i;
    const int bt = 7 - ((i + 1) & 7);
    if (l == 0) gate_crx(re, im, lane, bt, bc, c, s);
    else        gate_real(re, im, lane, bt, bc, c, -s, s, c); // CRY
  }

  // Measurement: <Z_q> = sum p * (+1 if bit(7-q)==0 else -1)
  float p0 = fmaf(re[0], re[0], im[0] * im[0]);
  float p1 = fmaf(re[1], re[1], im[1] * im[1]);
  float p2 = fmaf(re[2], re[2], im[2] * im[2]);
  float p3 = fmaf(re[3], re[3], im[3] * im[3]);
  float s4 = p0 + p1 + p2 + p3;

  float v[8];
#pragma unroll
  for (int q = 0; q < 6; ++q)           // bit 7-q is a lane bit (5-q)
    v[q] = ((lane >> (5 - q)) & 1) ? -s4 : s4;
  v[6] = p0 + p1 - p2 - p3;             // bit 1
  v[7] = p0 - p1 + p2 - p3;             // bit 0

  // group butterfly (d=1,2,4), then mux to 1 acc per lane, then cross-group.
#pragma unroll
  for (int d = 1; d < 8; d <<= 1) {
#pragma unroll
    for (int q = 0; q < 8; ++q) v[q] += shflx(v[q], d);
  }
  const int qs = lane & 7;
  float a0 = (qs & 1) ? v[1] : v[0];
  float a1 = (qs & 1) ? v[3] : v[2];
  float a2 = (qs & 1) ? v[5] : v[4];
  float a3 = (qs & 1) ? v[7] : v[6];
  float b0 = (qs & 2) ? a1 : a0;
  float b1 = (qs & 2) ? a3 : a2;
  float t  = (qs & 4) ? b1 : b0;
  t += shflx(t, 8);
  t += shflx(t, 16);
  t += shflx(t, 32);

  if (lane < 8) out[(size_t)b * 8 + lane] = t;
}

extern "C" void kernel_launch(void* const* d_in, const int* in_sizes, int n_in,
                              void* d_out, int out_size, void* d_ws, size_t ws_size,
                              hipStream_t stream) {
  const float* X = (const float*)d_in[0];   // (bs, 64) float32
  const float* W = (const float*)d_in[1];   // (2, 16) float32
  float* out = (float*)d_out;               // (bs, 8) float32
  int bs = in_sizes[0] / 64;
  const int waves_per_block = 4;
  const int threads = waves_per_block * 64;
  int blocks = (bs + waves_per_block - 1) / waves_per_block;
  hipLaunchKernelGGL(qsim_kernel, dim3(blocks), dim3(threads), 0, stream, X, W, out, bs);
}

// Round 3
// 77.683 us; speedup vs baseline: 1.9037x; 1.2228x over previous
//
#include <hip/hip_runtime.h>

#define DEV __device__ __forceinline__

DEV float shflx(float v, int m) { return __shfl_xor(v, m, 64); }
// VALU broadcast (v_readlane_b32 -> SGPR), no DS pipe.
DEV float rdlane(float v, int l) {
  return __int_as_float(__builtin_amdgcn_readlane(__float_as_int(v), l));
}

// real 2x2 [[m00,m01],[m10,m11]] on target bit bt, controlled on bit bc
DEV void gate_real(float re[4], float im[4], int lane, int bt, int bc,
                   float m00, float m01, float m10, float m11) {
  if (bt >= 2) {
    int sh = bt - 2, d = 1 << sh;
    int side = (lane >> sh) & 1;
    float cme = side ? m11 : m00;
    float cp  = side ? m10 : m01;
#pragma unroll
    for (int r = 0; r < 4; ++r) {
      float pr = shflx(re[r], d), pi = shflx(im[r], d);
      float nr = fmaf(cme, re[r], cp * pr);
      float ni = fmaf(cme, im[r], cp * pi);
      int idx = (lane << 2) | r;
      bool cb = (bc < 0) || (((idx >> bc) & 1) != 0);
      re[r] = cb ? nr : re[r];
      im[r] = cb ? ni : im[r];
    }
  } else {
#define PAIR_REAL(I, J) { \
      bool cb = (bc < 0) || (((((lane << 2) | (I)) >> bc) & 1) != 0); \
      float ar_ = re[I], ai_ = im[I], br_ = re[J], bi_ = im[J]; \
      float n0r = fmaf(m00, ar_, m01 * br_), n0i = fmaf(m00, ai_, m01 * bi_); \
      float n1r = fmaf(m10, ar_, m11 * br_), n1i = fmaf(m10, ai_, m11 * bi_); \
      re[I] = cb ? n0r : ar_; im[I] = cb ? n0i : ai_; \
      re[J] = cb ? n1r : br_; im[J] = cb ? n1i : bi_; }
    if (bt == 1) { PAIR_REAL(0, 2); PAIR_REAL(1, 3); }
    else         { PAIR_REAL(0, 1); PAIR_REAL(2, 3); }
#undef PAIR_REAL
  }
}

// controlled RX on target bit bt, control bit bc
DEV void gate_crx(float re[4], float im[4], int lane, int bt, int bc, float c, float s) {
  if (bt >= 2) {
    int sh = bt - 2, d = 1 << sh;
#pragma unroll
    for (int r = 0; r < 4; ++r) {
      float pr = shflx(re[r], d), pi = shflx(im[r], d);
      float nr = fmaf(c, re[r],  s * pi);
      float ni = fmaf(c, im[r], -s * pr);
      int idx = (lane << 2) | r;
      bool cb = ((idx >> bc) & 1) != 0;
      re[r] = cb ? nr : re[r];
      im[r] = cb ? ni : im[r];
    }
  } else {
#define PAIR_CRX(I, J) { \
      bool cb = (((((lane << 2) | (I)) >> bc) & 1) != 0); \
      float n0r = fmaf(c, re[I],  s * im[J]), n0i = fmaf(c, im[I], -s * re[J]); \
      float n1r = fmaf(c, re[J],  s * im[I]), n1i = fmaf(c, im[J], -s * re[I]); \
      re[I] = cb ? n0r : re[I]; im[I] = cb ? n0i : im[I]; \
      re[J] = cb ? n1r : re[J]; im[J] = cb ? n1i : im[J]; }
    if (bt == 1) { PAIR_CRX(0, 2); PAIR_CRX(1, 3); }
    else         { PAIR_CRX(0, 1); PAIR_CRX(2, 3); }
#undef PAIR_CRX
  }
}

// One wave simulates TWO batch elements (b0=2w, b1=2w+1), 4 complex amps/lane each.
// Amp index = (lane<<2)|r : bits 0,1 in-register, bits 2..7 = lane bits 0..5.
// Qubit q <-> bit 7-q.
__global__ __launch_bounds__(256) void qsim_kernel(const float* __restrict__ X,
                                                   const float* __restrict__ W,
                                                   float* __restrict__ out, int bs) {
  const int lane = threadIdx.x & 63;
  const int wave = blockIdx.x * (blockDim.x >> 6) + (threadIdx.x >> 6);
  const int b0 = wave * 2;
  if (b0 >= bs) return;

  // lane l holds sincos of encoding angle l, per element
  float x0 = X[(size_t)b0 * 64 + lane];
  float x1 = X[(size_t)b0 * 64 + 64 + lane];
  float sh0, ch0, sh1, ch1;
  __sincosf(0.5f * x0, &sh0, &ch0);
  __sincosf(0.5f * x1, &sh1, &ch1);

  // entangling weight sincos: lane (mod 16) holds weight (l*16 + i) for gate g=l*8+i
  float w = W[(((lane & 15) >> 3) << 4) + (lane & 7)];
  float sw, cw;
  __sincosf(0.5f * w, &sw, &cw);

  const float Hc = 0.70710678118654752440f;

  // ---- Encoding as product state ----
  // Chain in lane L (L<16): element e=L>>3, qubit q=L&7. Track column
  // (alpha,beta) of (R8..R0 H) |0>;  H|0> = (Hc, Hc).
  const int q = lane & 7;
  float car = Hc, cai = 0.f, cbr = Hc, cbi = 0.f;
#pragma unroll
  for (int i = 0; i < 9; ++i) {
    int idx = q * 9 + i;
    int idxc = idx > 63 ? 63 : idx;
    float c0 = __shfl(ch0, idxc, 64), s0 = __shfl(sh0, idxc, 64);
    float c1 = __shfl(ch1, idxc, 64), s1 = __shfl(sh1, idxc, 64);
    bool e1 = (lane & 8) != 0;
    float c = e1 ? c1 : c0;
    float s = e1 ? s1 : s0;
    float nar, nai, nbr, nbi;
    if ((i & 1) == 0) { // RZ: alpha *= (c - i s), beta *= (c + i s)
      nar = fmaf(car, c,  cai * s);
      nai = fmaf(cai, c, -car * s);
      nbr = fmaf(cbr, c, -cbi * s);
      nbi = fmaf(cbi, c,  cbr * s);
    } else {            // RY: a' = c a - s b ; b' = s a + c b
      nar = fmaf(c, car, -s * cbr);
      nai = fmaf(c, cai, -s * cbi);
      nbr = fmaf(s, car,  c * cbr);
      nbi = fmaf(s, cai,  c * cbi);
    }
    bool upd = (i == 0) || (q < 7);   // qubit 7 has only 1 rotation (idx 63)
    car = upd ? nar : car; cai = upd ? nai : cai;
    cbr = upd ? nbr : cbr; cbi = upd ? nbi : cbi;
  }

  // Build each lane's 4 amplitudes per element: product of per-qubit factors.
  float re[2][4], im[2][4];
#pragma unroll
  for (int e = 0; e < 2; ++e) {
    const int base = e * 8;
    // qubits 0..5 live on lane bits 5-q
    float Pr, Pi;
    {
      float a_r = rdlane(car, base), a_i = rdlane(cai, base);
      float b_r = rdlane(cbr, base), b_i = rdlane(cbi, base);
      bool bit = (lane >> 5) & 1;
      Pr = bit ? b_r : a_r; Pi = bit ? b_i : a_i;
    }
#pragma unroll
    for (int qq = 1; qq <= 5; ++qq) {
      float a_r = rdlane(car, base + qq), a_i = rdlane(cai, base + qq);
      float b_r = rdlane(cbr, base + qq), b_i = rdlane(cbi, base + qq);
      bool bit = (lane >> (5 - qq)) & 1;
      float fr = bit ? b_r : a_r, fi = bit ? b_i : a_i;
      float nr = Pr * fr - Pi * fi;
      float ni = Pr * fi + Pi * fr;
      Pr = nr; Pi = ni;
    }
    float a6r = rdlane(car, base + 6), a6i = rdlane(cai, base + 6);
    float b6r = rdlane(cbr, base + 6), b6i = rdlane(cbi, base + 6);
    float a7r = rdlane(car, base + 7), a7i = rdlane(cai, base + 7);
    float b7r = rdlane(cbr, base + 7), b7i = rdlane(cbi, base + 7);
    // r bit1 <-> qubit 6, r bit0 <-> qubit 7
    float t0r = Pr * a6r - Pi * a6i, t0i = Pr * a6i + Pi * a6r;
    float t1r = Pr * b6r - Pi * b6i, t1i = Pr * b6i + Pi * b6r;
    re[e][0] = t0r * a7r - t0i * a7i; im[e][0] = t0r * a7i + t0i * a7r;
    re[e][1] = t0r * b7r - t0i * b7i; im[e][1] = t0r * b7i + t0i * b7r;
    re[e][2] = t1r * a7r - t1i * a7i; im[e][2] = t1r * a7i + t1i * a7r;
    re[e][3] = t1r * b7r - t1i * b7i; im[e][3] = t1r * b7i + t1i * b7r;
  }

  // ---- Entangling: layer 0 = CRX, layer 1 = CRY; control=i, target=(i+1)%8 ----
#pragma unroll
  for (int g = 0; g < 16; ++g) {
    const int l = g >> 3, i = g & 7;
    float c = rdlane(cw, g);
    float s = rdlane(sw, g);
    const int bc = 7 - i;
    const int bt = 7 - ((i + 1) & 7);
#pragma unroll
    for (int e = 0; e < 2; ++e) {
      if (l == 0) gate_crx(re[e], im[e], lane, bt, bc, c, s);
      else        gate_real(re[e], im[e], lane, bt, bc, c, -s, s, c); // CRY
    }
  }

  // ---- Measurement ----
  // Qubits 0..5 (lane bits 5..0): WHT of s4 at masks 32,16,8,4,2,1.
  // Qubits 6,7 (r bits 1,0): plain sums of d6,d7.
  float whtv[2], d6s[2], d7s[2];
#pragma unroll
  for (int e = 0; e < 2; ++e) {
    float p0 = fmaf(re[e][0], re[e][0], im[e][0] * im[e][0]);
    float p1 = fmaf(re[e][1], re[e][1], im[e][1] * im[e][1]);
    float p2 = fmaf(re[e][2], re[e][2], im[e][2] * im[e][2]);
    float p3 = fmaf(re[e][3], re[e][3], im[e][3] * im[e][3]);
    float t01 = p0 + p1, t23 = p2 + p3;
    float s4 = t01 + t23;
    float d6 = t01 - t23;
    float d7 = (p0 + p2) - (p1 + p3);
    float wv = s4;
#pragma unroll
    for (int k = 0; k < 6; ++k) {
      float p = shflx(wv, 1 << k);
      float neg = ((lane >> k) & 1) ? -wv : wv;
      wv = p + neg;
    }
#pragma unroll
    for (int d = 1; d < 64; d <<= 1) {
      d6 += shflx(d6, d);
      d7 += shflx(d7, d);
    }
    whtv[e] = wv; d6s[e] = d6; d7s[e] = d7;
  }

  // Gather outputs: lanes 0..7 -> element 0 qubits 0..7, lanes 8..15 -> element 1.
  const int qs = lane & 7;
  const int src = 32 >> qs;               // qubit q value sits in WHT lane 32>>q (q<6)
  float g0 = __shfl(whtv[0], src, 64);
  float g1 = __shfl(whtv[1], src, 64);
  float v0 = (qs == 6) ? d6s[0] : (qs == 7) ? d7s[0] : g0;
  float v1 = (qs == 6) ? d6s[1] : (qs == 7) ? d7s[1] : g1;
  float val = (lane & 8) ? v1 : v0;
  if (lane < 16) out[(size_t)b0 * 8 + lane] = val;
}

extern "C" void kernel_launch(void* const* d_in, const int* in_sizes, int n_in,
                              void* d_out, int out_size, void* d_ws, size_t ws_size,
                              hipStream_t stream) {
  const float* X = (const float*)d_in[0];   // (bs, 64) float32
  const float* W = (const float*)d_in[1];   // (2, 16) float32
  float* out = (float*)d_out;               // (bs, 8) float32
  int bs = in_sizes[0] / 64;
  int waves = (bs + 1) / 2;                 // 2 elements per wave
  const int waves_per_block = 4;
  const int threads = waves_per_block * 64;
  int blocks = (waves + waves_per_block - 1) / waves_per_block;
  hipLaunchKernelGGL(qsim_kernel, dim3(blocks), dim3(threads), 0, stream, X, W, out, bs);
}

// Round 4
// 75.762 us; speedup vs baseline: 1.9520x; 1.0254x over previous
//
#include <hip/hip_runtime.h>

#define DEV __device__ __forceinline__
typedef float f32x2 __attribute__((ext_vector_type(2)));
typedef float f32x4 __attribute__((ext_vector_type(4)));

DEV float shflx(float v, int m) { return __shfl_xor(v, m, 64); }
DEV float rdlane(float v, int l) {
  return __int_as_float(__builtin_amdgcn_readlane(__float_as_int(v), l));
}
DEV f32x2 pkfma(f32x2 a, f32x2 b, f32x2 c) { return __builtin_elementwise_fma(a, b, c); }
DEV f32x2 splat(float x) { return (f32x2){x, x}; }
DEV f32x2 swap2(f32x2 v) { return __builtin_shufflevector(v, v, 1, 0); }
// complex multiply P*F
DEV f32x2 cmul(f32x2 P, f32x2 F) {
  f32x2 t = swap2(P);
  f32x2 m = {-t.x, t.y};                    // (-Py, Px)
  return pkfma(splat(F.y), m, splat(F.x) * P);
}

// One wave simulates FOUR batch elements. 256 amps each, amp idx = (lane<<2)|r:
// bits 0,1 in-register (qubits 7,6), bits 2..7 = lane bits 0..5 (qubits 5..0).
__global__ __launch_bounds__(256) void qsim_kernel(const float* __restrict__ X,
                                                   const float* __restrict__ W,
                                                   float* __restrict__ out, int bs) {
  const int lane = threadIdx.x & 63;
  const int wave = blockIdx.x * (blockDim.x >> 6) + (threadIdx.x >> 6);
  const int b0 = wave * 4;
  if (b0 >= bs) return;
  const int nElem = (bs - b0) < 4 ? (bs - b0) : 4;

  // ---- entangling weight sincos: lane (mod 16) holds gate (lane&15) ----
  float w = W[(((lane & 15) >> 3) << 4) + (lane & 7)];
  float sw, cw;
  __sincosf(0.5f * w, &sw, &cw);

  // ---- encoding chains: lane L<32 -> element (L>>3), qubit (L&7); 32..63 replicate ----
  const int ce = (lane >> 3) & 3;
  const int cq = lane & 7;
  int bb = b0 + ce; bb = bb >= bs ? bs - 1 : bb;
  const float* Xrow = X + (size_t)bb * 64;
  float ang[9];
#pragma unroll
  for (int i = 0; i < 9; ++i) {
    int idx = cq * 9 + i;                 // lane's 9 angles are CONTIGUOUS in X
    idx = idx > 63 ? 63 : idx;            // qubit 7 has only 1 rotation
    ang[i] = Xrow[idx];
  }
  const float Hc = 0.70710678118654752440f;
  f32x2 A = {Hc, 0.f}, B = {Hc, 0.f};     // column of (rotations * H) |0>
#pragma unroll
  for (int i = 0; i < 9; ++i) {
    float s, c;
    __sincosf(0.5f * ang[i], &s, &c);
    if (i > 0) {                          // qubit-7 chain: identity after i=0
      bool dead = (cq == 7);
      c = dead ? 1.f : c;
      s = dead ? 0.f : s;
    }
    if ((i & 1) == 0) {                   // RZ: A *= (c - i s), B *= (c + i s)
      f32x2 nA = pkfma((f32x2){s, -s}, swap2(A), splat(c) * A);
      f32x2 nB = pkfma((f32x2){-s, s}, swap2(B), splat(c) * B);
      A = nA; B = nB;
    } else {                              // RY: A' = cA - sB ; B' = sA + cB
      f32x2 nA = pkfma(splat(-s), B, splat(c) * A);
      f32x2 nB = pkfma(splat(c), B, splat(s) * A);
      A = nA; B = nB;
    }
  }

  // publish chain results: 512 B per wave
  __shared__ f32x4 ldsAB[4][32];
  const int wvid = (threadIdx.x >> 6) & 3;
  if (lane < 32) ldsAB[wvid][lane] = (f32x4){A.x, A.y, B.x, B.y};
  __builtin_amdgcn_wave_barrier();        // same-wave DS ordering fence (no HW cost)

  // ---- build product-state amplitudes ----
  const f32x2* base = (const f32x2*)&ldsAB[wvid][0];
  f32x2 amp[4][4];
#pragma unroll
  for (int e = 0; e < 4; ++e) {
    int bit0 = (lane >> 5) & 1;
    f32x2 P = base[(e * 8 + 0) * 2 + bit0];
#pragma unroll
    for (int q = 1; q <= 5; ++q) {
      int bit = (lane >> (5 - q)) & 1;
      P = cmul(P, base[(e * 8 + q) * 2 + bit]);
    }
    f32x4 F6 = ldsAB[wvid][e * 8 + 6];
    f32x4 F7 = ldsAB[wvid][e * 8 + 7];
    f32x2 A6 = {F6.x, F6.y}, B6 = {F6.z, F6.w};
    f32x2 A7 = {F7.x, F7.y}, B7 = {F7.z, F7.w};
    f32x2 t0 = cmul(P, A6), t1 = cmul(P, B6);
    amp[e][0] = cmul(t0, A7);             // r bit1 <-> qubit 6, r bit0 <-> qubit 7
    amp[e][1] = cmul(t0, B7);
    amp[e][2] = cmul(t1, A7);
    amp[e][3] = cmul(t1, B7);
  }

  // ---- entangling: layer 0 = CRX, layer 1 = CRY; control=i, target=(i+1)%8 ----
#pragma unroll
  for (int l = 0; l < 2; ++l) {
    const bool isCRX = (l == 0);
#pragma unroll
    for (int i = 0; i < 8; ++i) {
      const float cg = rdlane(cw, l * 8 + i);
      const float sg = rdlane(sw, l * 8 + i);
      if (i <= 4) {                       // control lane bit 5-i, target lane bit 4-i
        const int d = 1 << (4 - i);
        const bool act = (lane >> (5 - i)) & 1;
        const float c1 = act ? cg : 1.f;  // hoisted: inactive lanes get identity
        const float s1 = act ? sg : 0.f;
        const f32x2 C2 = splat(c1);
        if (isCRX) {
          const f32x2 S2 = {s1, -s1};
#pragma unroll
          for (int e = 0; e < 4; ++e)
#pragma unroll
            for (int r = 0; r < 4; ++r) {
              f32x2 p;
              p.x = shflx(amp[e][r].y, d);   // (pi, pr): swap folded into shuffle
              p.y = shflx(amp[e][r].x, d);
              amp[e][r] = pkfma(S2, p, C2 * amp[e][r]);
            }
        } else {
          const bool side = (lane >> (4 - i)) & 1;
          const float sp = side ? s1 : -s1;
          const f32x2 SP = splat(sp);
#pragma unroll
          for (int e = 0; e < 4; ++e)
#pragma unroll
            for (int r = 0; r < 4; ++r) {
              f32x2 p;
              p.x = shflx(amp[e][r].x, d);
              p.y = shflx(amp[e][r].y, d);
              amp[e][r] = pkfma(SP, p, C2 * amp[e][r]);
            }
        }
      } else if (i == 5) {                // control lane bit 0, target = r bit1
        const bool act = lane & 1;
        const float c1 = act ? cg : 1.f;
        const float s1 = act ? sg : 0.f;
        const f32x2 C2 = splat(c1);
#pragma unroll
        for (int e = 0; e < 4; ++e) {
          f32x2 A0 = amp[e][0], A1 = amp[e][1], A2 = amp[e][2], A3 = amp[e][3];
          if (isCRX) {
            const f32x2 S2 = {s1, -s1};
            amp[e][0] = pkfma(S2, swap2(A2), C2 * A0);
            amp[e][2] = pkfma(S2, swap2(A0), C2 * A2);
            amp[e][1] = pkfma(S2, swap2(A3), C2 * A1);
            amp[e][3] = pkfma(S2, swap2(A1), C2 * A3);
          } else {
            const f32x2 SN = splat(-s1), SPp = splat(s1);
            amp[e][0] = pkfma(SN, A2, C2 * A0);
            amp[e][2] = pkfma(SPp, A0, C2 * A2);
            amp[e][1] = pkfma(SN, A3, C2 * A1);
            amp[e][3] = pkfma(SPp, A1, C2 * A3);
          }
        }
      } else if (i == 6) {                // control r bit1, target r bit0: only pair (2,3)
        const f32x2 C2 = splat(cg);
#pragma unroll
        for (int e = 0; e < 4; ++e) {
          f32x2 A2 = amp[e][2], A3 = amp[e][3];
          if (isCRX) {
            const f32x2 S2 = {sg, -sg};
            amp[e][2] = pkfma(S2, swap2(A3), C2 * A2);
            amp[e][3] = pkfma(S2, swap2(A2), C2 * A3);
          } else {
            amp[e][2] = pkfma(splat(-sg), A3, C2 * A2);
            amp[e][3] = pkfma(splat(sg), A2, C2 * A3);
          }
        }
      } else {                            // i == 7: control r bit0 (r=1,3), target lane bit 5
        const f32x2 C2 = splat(cg);
        if (isCRX) {
          const f32x2 S2 = {sg, -sg};
#pragma unroll
          for (int e = 0; e < 4; ++e)
#pragma unroll
            for (int r = 1; r < 4; r += 2) {
              f32x2 p;
              p.x = shflx(amp[e][r].y, 32);
              p.y = shflx(amp[e][r].x, 32);
              amp[e][r] = pkfma(S2, p, C2 * amp[e][r]);
            }
        } else {
          const bool side = (lane >> 5) & 1;
          const float sp = side ? sg : -sg;
          const f32x2 SP = splat(sp);
#pragma unroll
          for (int e = 0; e < 4; ++e)
#pragma unroll
            for (int r = 1; r < 4; r += 2) {
              f32x2 p;
              p.x = shflx(amp[e][r].x, 32);
              p.y = shflx(amp[e][r].y, 32);
              amp[e][r] = pkfma(SP, p, C2 * amp[e][r]);
            }
        }
      }
    }
  }

  // ---- measurement ----
  float whtv[4], d6s[4], d7s[4];
#pragma unroll
  for (int e = 0; e < 4; ++e) {
    float p0 = fmaf(amp[e][0].x, amp[e][0].x, amp[e][0].y * amp[e][0].y);
    float p1 = fmaf(amp[e][1].x, amp[e][1].x, amp[e][1].y * amp[e][1].y);
    float p2 = fmaf(amp[e][2].x, amp[e][2].x, amp[e][2].y * amp[e][2].y);
    float p3 = fmaf(amp[e][3].x, amp[e][3].x, amp[e][3].y * amp[e][3].y);
    float t01 = p0 + p1, t23 = p2 + p3;
    float s4 = t01 + t23;
    float d6 = t01 - t23;                 // qubit 6 (r bit1)
    float d7 = (p0 + p2) - (p1 + p3);     // qubit 7 (r bit0)
    float wv_ = s4;                       // WHT over lane bits -> qubits 0..5
#pragma unroll
    for (int k = 0; k < 6; ++k) {
      float pp = shflx(wv_, 1 << k);
      float neg = ((lane >> k) & 1) ? -wv_ : wv_;
      wv_ = pp + neg;
    }
#pragma unroll
    for (int d = 1; d < 64; d <<= 1) { d6 += shflx(d6, d); d7 += shflx(d7, d); }
    whtv[e] = wv_; d6s[e] = d6; d7s[e] = d7;
  }

  // ---- gather & store: lanes 0..31 -> 4 rows x 8 qubits, coalesced 128B ----
  const int qs = lane & 7;
  const int eid = lane >> 3;
  const int src = 32 >> qs;               // qubit q (<6) sits in WHT lane 32>>q
  float outv = 0.f;
#pragma unroll
  for (int e = 0; e < 4; ++e) {
    float g = __shfl(whtv[e], src, 64);
    float v = (qs == 6) ? d6s[e] : (qs == 7) ? d7s[e] : g;
    outv = (eid == e) ? v : outv;
  }
  if (eid < nElem) out[(size_t)b0 * 8 + lane] = outv;
}

extern "C" void kernel_launch(void* const* d_in, const int* in_sizes, int n_in,
                              void* d_out, int out_size, void* d_ws, size_t ws_size,
                              hipStream_t stream) {
  const float* X = (const float*)d_in[0];   // (bs, 64) float32
  const float* W = (const float*)d_in[1];   // (2, 16) float32
  float* out = (float*)d_out;               // (bs, 8) float32
  int bs = in_sizes[0] / 64;
  int waves = (bs + 3) / 4;                 // 4 elements per wave
  const int waves_per_block = 4;
  const int threads = waves_per_block * 64;
  int blocks = (waves + waves_per_block - 1) / waves_per_block;
  hipLaunchKernelGGL(qsim_kernel, dim3(blocks), dim3(threads), 0, stream, X, W, out, bs);
}

// Round 5
// 67.076 us; speedup vs baseline: 2.2048x; 1.1295x over previous
//
#include <hip/hip_runtime.h>

#define DEV __device__ __forceinline__
typedef float f32x2 __attribute__((ext_vector_type(2)));
typedef float f32x4 __attribute__((ext_vector_type(4)));

DEV float shflx(float v, int m) { return __shfl_xor(v, m, 64); }
DEV float rdlane(float v, int l) {
  return __int_as_float(__builtin_amdgcn_readlane(__float_as_int(v), l));
}
DEV f32x2 pkfma(f32x2 a, f32x2 b, f32x2 c) { return __builtin_elementwise_fma(a, b, c); }
DEV f32x2 splat(float x) { return (f32x2){x, x}; }
DEV f32x2 swap2(f32x2 v) { return __builtin_shufflevector(v, v, 1, 0); }
DEV f32x2 cmul(f32x2 P, f32x2 F) {           // complex multiply P*F
  f32x2 t = swap2(P);
  f32x2 m = {-t.x, t.y};
  return pkfma(splat(F.y), m, splat(F.x) * P);
}

// lane-xor data movement: DPP (pure VALU, no DS wait) where the pattern allows.
template <int CTRL>
DEV float dppmov(float v) {
  return __int_as_float(__builtin_amdgcn_update_dpp(
      0, __float_as_int(v), CTRL, 0xf, 0xf, true));
}
template <int M>
DEV float xorl(float v) {
  if constexpr (M == 1)      return dppmov<0xB1>(v);   // quad_perm [1,0,3,2]
  else if constexpr (M == 2) return dppmov<0x4E>(v);   // quad_perm [2,3,0,1]
  else if constexpr (M == 8) return dppmov<0x128>(v);  // row_ror:8 == xor 8 (row=16)
  else                       return shflx(v, M);       // 4,16 -> ds_swizzle; 32 -> bpermute
}

// Controlled rotation with target on a LANE bit (mask D). c1/s1 already
// masked by the control bit at the call site (inactive lanes: c1=1,s1=0).
// CRX: new = c*me + i*s*partner (sign folded via swapped fetch)
// CRY: new = c*me + (-1)^(1-tbit) * s * partner
template <int D, bool CRX, int R0, int RS>
DEV void gate_x(f32x2 amp[2][4], int lane, float c1, float s1) {
  const f32x2 C2 = splat(c1);
  if constexpr (CRX) {
    const f32x2 S2 = {s1, -s1};
#pragma unroll
    for (int e = 0; e < 2; ++e)
#pragma unroll
      for (int r = R0; r < 4; r += RS) {
        f32x2 p;
        p.x = xorl<D>(amp[e][r].y);      // swap folded into the fetch
        p.y = xorl<D>(amp[e][r].x);
        amp[e][r] = pkfma(S2, p, C2 * amp[e][r]);
      }
  } else {
    const float sp = (lane & D) ? s1 : -s1;
    const f32x2 SP = splat(sp);
#pragma unroll
    for (int e = 0; e < 2; ++e)
#pragma unroll
      for (int r = R0; r < 4; r += RS) {
        f32x2 p;
        p.x = xorl<D>(amp[e][r].x);
        p.y = xorl<D>(amp[e][r].y);
        amp[e][r] = pkfma(SP, p, C2 * amp[e][r]);
      }
  }
}

// One wave simulates TWO batch elements. 256 amps each, amp idx = (lane<<2)|r:
// r bits (1,0) <-> qubits (6,7); lane bits 5..0 <-> qubits 0..5.
__global__ __launch_bounds__(256, 8) void qsim_kernel(const float* __restrict__ X,
                                                      const float* __restrict__ W,
                                                      float* __restrict__ out, int bs) {
  const int lane = threadIdx.x & 63;
  const int wave = blockIdx.x * (blockDim.x >> 6) + (threadIdx.x >> 6);
  const int b0 = wave * 2;
  if (b0 >= bs) return;

  // ---- entangling weight sincos: lane (mod 16) holds gate (lane&15) ----
  float w = W[(((lane & 15) >> 3) << 4) + (lane & 7)];
  float sw, cw;
  __sincosf(0.5f * w, &sw, &cw);

  // ---- encoding chains: lane -> element (lane>>3)&1, qubit lane&7 ----
  const int ce = (lane >> 3) & 1;
  const int cq = lane & 7;
  int bb = b0 + ce; bb = bb >= bs ? bs - 1 : bb;
  const float* Xrow = X + (size_t)bb * 64;
  float ang[9];
#pragma unroll
  for (int i = 0; i < 9; ++i) {
    int idx = cq * 9 + i;                // lane's 9 angles are contiguous in X
    idx = idx > 63 ? 63 : idx;           // qubit 7 has only 1 rotation
    ang[i] = Xrow[idx];
  }
  const float Hc = 0.70710678118654752440f;
  f32x2 A = {Hc, 0.f}, B = {Hc, 0.f};    // column of (rotations * H)|0>
#pragma unroll
  for (int i = 0; i < 9; ++i) {
    float s, c;
    __sincosf(0.5f * ang[i], &s, &c);
    if (i > 0) {                         // qubit-7 chain: identity after i=0
      bool dead = (cq == 7);
      c = dead ? 1.f : c;
      s = dead ? 0.f : s;
    }
    if ((i & 1) == 0) {                  // RZ
      f32x2 nA = pkfma((f32x2){s, -s}, swap2(A), splat(c) * A);
      f32x2 nB = pkfma((f32x2){-s, s}, swap2(B), splat(c) * B);
      A = nA; B = nB;
    } else {                             // RY
      f32x2 nA = pkfma(splat(-s), B, splat(c) * A);
      f32x2 nB = pkfma(splat(c), B, splat(s) * A);
      A = nA; B = nB;
    }
  }

  // publish chain results: 256 B per wave
  __shared__ f32x4 ldsAB[4][16];
  const int wvid = (threadIdx.x >> 6) & 3;
  if (lane < 16) ldsAB[wvid][lane] = (f32x4){A.x, A.y, B.x, B.y};
  __builtin_amdgcn_wave_barrier();       // same-wave DS ordering fence

  // ---- build product-state amplitudes ----
  const f32x2* base = (const f32x2*)&ldsAB[wvid][0];
  f32x2 amp[2][4];
#pragma unroll
  for (int e = 0; e < 2; ++e) {
    int bit0 = (lane >> 5) & 1;
    f32x2 P = base[(e * 8 + 0) * 2 + bit0];
#pragma unroll
    for (int q = 1; q <= 5; ++q) {
      int bit = (lane >> (5 - q)) & 1;
      P = cmul(P, base[(e * 8 + q) * 2 + bit]);
    }
    f32x4 F6 = ldsAB[wvid][e * 8 + 6];
    f32x4 F7 = ldsAB[wvid][e * 8 + 7];
    f32x2 A6 = {F6.x, F6.y}, B6 = {F6.z, F6.w};
    f32x2 A7 = {F7.x, F7.y}, B7 = {F7.z, F7.w};
    f32x2 t0 = cmul(P, A6), t1 = cmul(P, B6);
    amp[e][0] = cmul(t0, A7);            // r bit1 <-> qubit 6, r bit0 <-> qubit 7
    amp[e][1] = cmul(t0, B7);
    amp[e][2] = cmul(t1, A7);
    amp[e][3] = cmul(t1, B7);
  }

  // ---- entangling: layer 0 = CRX, layer 1 = CRY; control=i, target=(i+1)%8 ----
#define LANE_GATE(G, CBIT, D)                                         \
  {                                                                   \
    const float cg = rdlane(cw, G), sg = rdlane(sw, G);               \
    const bool act = (lane >> (CBIT)) & 1;                            \
    const float c1 = act ? cg : 1.f, s1 = act ? sg : 0.f;             \
    if (isCRX) gate_x<D, true, 0, 1>(amp, lane, c1, s1);              \
    else       gate_x<D, false, 0, 1>(amp, lane, c1, s1);             \
  }
#pragma unroll
  for (int l = 0; l < 2; ++l) {
    const bool isCRX = (l == 0);
    LANE_GATE(l * 8 + 0, 5, 16)          // ctrl q0(lane5) -> tgt q1(lane4)
    LANE_GATE(l * 8 + 1, 4, 8)           // DPP row_ror:8
    LANE_GATE(l * 8 + 2, 3, 4)
    LANE_GATE(l * 8 + 3, 2, 2)           // DPP quad_perm
    LANE_GATE(l * 8 + 4, 1, 1)           // DPP quad_perm
    {                                    // i=5: ctrl lane bit0, tgt r bit1 (pairs 0<->2, 1<->3)
      const float cg = rdlane(cw, l * 8 + 5), sg = rdlane(sw, l * 8 + 5);
      const bool act = lane & 1;
      const float c1 = act ? cg : 1.f, s1 = act ? sg : 0.f;
      const f32x2 C2 = splat(c1);
#pragma unroll
      for (int e = 0; e < 2; ++e) {
        f32x2 A0 = amp[e][0], A1 = amp[e][1], A2 = amp[e][2], A3 = amp[e][3];
        if (isCRX) {
          const f32x2 S2 = {s1, -s1};
          amp[e][0] = pkfma(S2, swap2(A2), C2 * A0);
          amp[e][2] = pkfma(S2, swap2(A0), C2 * A2);
          amp[e][1] = pkfma(S2, swap2(A3), C2 * A1);
          amp[e][3] = pkfma(S2, swap2(A1), C2 * A3);
        } else {
          amp[e][0] = pkfma(splat(-s1), A2, C2 * A0);
          amp[e][2] = pkfma(splat(s1), A0, C2 * A2);
          amp[e][1] = pkfma(splat(-s1), A3, C2 * A1);
          amp[e][3] = pkfma(splat(s1), A1, C2 * A3);
        }
      }
    }
    {                                    // i=6: ctrl r bit1, tgt r bit0 (pair 2<->3 only)
      const float cg = rdlane(cw, l * 8 + 6), sg = rdlane(sw, l * 8 + 6);
      const f32x2 C2 = splat(cg);
#pragma unroll
      for (int e = 0; e < 2; ++e) {
        f32x2 A2 = amp[e][2], A3 = amp[e][3];
        if (isCRX) {
          const f32x2 S2 = {sg, -sg};
          amp[e][2] = pkfma(S2, swap2(A3), C2 * A2);
          amp[e][3] = pkfma(S2, swap2(A2), C2 * A3);
        } else {
          amp[e][2] = pkfma(splat(-sg), A3, C2 * A2);
          amp[e][3] = pkfma(splat(sg), A2, C2 * A3);
        }
      }
    }
    {                                    // i=7: ctrl r bit0 (r=1,3), tgt lane bit5
      const float cg = rdlane(cw, l * 8 + 7), sg = rdlane(sw, l * 8 + 7);
      if (isCRX) gate_x<32, true, 1, 2>(amp, lane, cg, sg);
      else       gate_x<32, false, 1, 2>(amp, lane, cg, sg);
    }
  }
#undef LANE_GATE

  // ---- measurement ----
  float whtv[2], d6s[2], d7s[2];
#pragma unroll
  for (int e = 0; e < 2; ++e) {
    float p0 = fmaf(amp[e][0].x, amp[e][0].x, amp[e][0].y * amp[e][0].y);
    float p1 = fmaf(amp[e][1].x, amp[e][1].x, amp[e][1].y * amp[e][1].y);
    float p2 = fmaf(amp[e][2].x, amp[e][2].x, amp[e][2].y * amp[e][2].y);
    float p3 = fmaf(amp[e][3].x, amp[e][3].x, amp[e][3].y * amp[e][3].y);
    float t01 = p0 + p1, t23 = p2 + p3;
    float wv = t01 + t23;                // WHT input (qubits 0..5 on lane bits)
    f32x2 D = {t01 - t23,                // qubit 6 (r bit1)
               (p0 + p2) - (p1 + p3)};   // qubit 7 (r bit0)
#define STAGE(K, M)                                         \
    {                                                       \
      float pp = xorl<M>(wv);                               \
      wv = pp + (((lane >> K) & 1) ? -wv : wv);             \
      f32x2 pd;                                             \
      pd.x = xorl<M>(D.x);                                  \
      pd.y = xorl<M>(D.y);                                  \
      D = D + pd;                                           \
    }
    STAGE(0, 1) STAGE(1, 2) STAGE(2, 4) STAGE(3, 8) STAGE(4, 16) STAGE(5, 32)
#undef STAGE
    whtv[e] = wv; d6s[e] = D.x; d7s[e] = D.y;
  }

  // ---- gather & store: lanes 0..15 -> 2 rows x 8 qubits ----
  const int qs = lane & 7;
  const int eid = (lane >> 3) & 1;
  const int src = 32 >> qs;              // qubit q (<6) sits in WHT lane 32>>q
  float g0 = __shfl(whtv[0], src, 64);
  float g1 = __shfl(whtv[1], src, 64);
  float v0 = (qs == 6) ? d6s[0] : (qs == 7) ? d7s[0] : g0;
  float v1 = (qs == 6) ? d6s[1] : (qs == 7) ? d7s[1] : g1;
  float val = eid ? v1 : v0;
  if (lane < 16 && (b0 + eid) < bs) out[(size_t)b0 * 8 + lane] = val;
}

extern "C" void kernel_launch(void* const* d_in, const int* in_sizes, int n_in,
                              void* d_out, int out_size, void* d_ws, size_t ws_size,
                              hipStream_t stream) {
  const float* X = (const float*)d_in[0];   // (bs, 64) float32
  const float* W = (const float*)d_in[1];   // (2, 16) float32
  float* out = (float*)d_out;               // (bs, 8) float32
  int bs = in_sizes[0] / 64;
  int waves = (bs + 1) / 2;                 // 2 elements per wave
  const int waves_per_block = 4;
  const int threads = waves_per_block * 64;
  int blocks = (waves + waves_per_block - 1) / waves_per_block;
  hipLaunchKernelGGL(qsim_kernel, dim3(blocks), dim3(threads), 0, stream, X, W, out, bs);
}

// Round 6
// 64.867 us; speedup vs baseline: 2.2799x; 1.0340x over previous
//
#include <hip/hip_runtime.h>

#define DEV __device__ __forceinline__
typedef float f32x2 __attribute__((ext_vector_type(2)));
typedef float f32x4 __attribute__((ext_vector_type(4)));

DEV float rdlane(float v, int l) {
  return __int_as_float(__builtin_amdgcn_readlane(__float_as_int(v), l));
}
DEV f32x2 pkfma(f32x2 a, f32x2 b, f32x2 c) { return __builtin_elementwise_fma(a, b, c); }
DEV f32x2 splat(float x) { return (f32x2){x, x}; }
DEV f32x2 swap2(f32x2 v) { return __builtin_shufflevector(v, v, 1, 0); }
DEV f32x2 cmul(f32x2 P, f32x2 F) {            // complex multiply P*F
  f32x2 t = swap2(P);
  f32x2 m = {-t.x, t.y};
  return pkfma(splat(F.y), m, splat(F.x) * P);
}

template <int CTRL>
DEV float dppmov(float v) {                   // pure-VALU lane move
  return __int_as_float(__builtin_amdgcn_update_dpp(
      0, __float_as_int(v), CTRL, 0xf, 0xf, true));
}
// xor-mask lane exchange. 1,2 = quad_perm DPP; 8 = row_ror:8 DPP;
// 4,16 = ds_swizzle immediate (no addr math, stays within 32-lane group).
template <int M>
DEV float xorl(float v) {
  if constexpr (M == 1)       return dppmov<0xB1>(v);
  else if constexpr (M == 2)  return dppmov<0x4E>(v);
  else if constexpr (M == 8)  return dppmov<0x128>(v);
  else if constexpr (M == 4)
    return __int_as_float(__builtin_amdgcn_ds_swizzle(__float_as_int(v), 0x101F));
  else /* M == 16 */
    return __int_as_float(__builtin_amdgcn_ds_swizzle(__float_as_int(v), 0x401F));
}

// Controlled rotation, target on LANE bit M. c1/s1 pre-masked by control
// (inactive lanes: c1=1, s1=0) unless control is an r-bit (R0/RS restrict r).
template <int M, bool CRX, int R0, int RS>
DEV void gate_lane(f32x2 amp[8], int lane, float c1, float s1) {
  const f32x2 C2 = splat(c1);
  if constexpr (CRX) {
    const f32x2 S2 = {s1, -s1};
#pragma unroll
    for (int r = R0; r < 8; r += RS) {
      f32x2 p;
      p.x = xorl<M>(amp[r].y);                // (p.im, p.re): swap folded in
      p.y = xorl<M>(amp[r].x);
      amp[r] = pkfma(S2, p, C2 * amp[r]);
    }
  } else {
    const float sp = (lane & M) ? s1 : -s1;
    const f32x2 SP = splat(sp);
#pragma unroll
    for (int r = R0; r < 8; r += RS) {
      f32x2 p;
      p.x = xorl<M>(amp[r].x);
      p.y = xorl<M>(amp[r].y);
      amp[r] = pkfma(SP, p, C2 * amp[r]);
    }
  }
}

// Controlled rotation, target on an r-bit: pair (I: tbit=0, J: tbit=1).
template <bool CRX>
DEV void gate_pair(f32x2& aI, f32x2& aJ, float c1, float s1) {
  const f32x2 C2 = splat(c1);
  f32x2 nI, nJ;
  if constexpr (CRX) {
    const f32x2 S2 = {s1, -s1};
    nI = pkfma(S2, swap2(aJ), C2 * aI);
    nJ = pkfma(S2, swap2(aI), C2 * aJ);
  } else {
    nI = pkfma(splat(-s1), aJ, C2 * aI);
    nJ = pkfma(splat(s1), aI, C2 * aJ);
  }
  aI = nI; aJ = nJ;
}

// One wave = TWO batch elements, one per 32-lane half (element = lane bit 5).
// Per lane: 8 complex amps (f32x2). Amp bits: lane bits 4..0 = qubits 0..4,
// r bits 2,1,0 = qubits 5,6,7.
__global__ __launch_bounds__(256, 8) void qsim_kernel(const float* __restrict__ X,
                                                      const float* __restrict__ W,
                                                      float* __restrict__ out, int bs) {
  const int lane = threadIdx.x & 63;
  const int wave = blockIdx.x * (blockDim.x >> 6) + (threadIdx.x >> 6);
  const int b0 = wave * 2;
  if (b0 >= bs) return;

  // ---- entangling weight sincos: lane g<16 holds gate g = l*8+i -> W[l*16+i] ----
  float w = W[(((lane & 15) >> 3) << 4) + (lane & 7)];
  float sw, cw;
  __sincosf(0.5f * w, &sw, &cw);

  // ---- encoding chains: lane -> element (lane>>3)&1, qubit lane&7 (16 chains) ----
  const int ce = (lane >> 3) & 1;
  const int cq = lane & 7;
  int bb = b0 + ce; bb = bb >= bs ? bs - 1 : bb;
  const float* Xrow = X + (size_t)bb * 64;
  float ang[9];
#pragma unroll
  for (int i = 0; i < 9; ++i) {
    int idx = cq * 9 + i;                 // this chain's 9 angles are contiguous
    idx = idx > 63 ? 63 : idx;            // qubit 7 has only 1 rotation
    ang[i] = Xrow[idx];
  }
  const float Hc = 0.70710678118654752440f;
  f32x2 A = {Hc, 0.f}, B = {Hc, 0.f};     // column of (rotations * H)|0>
#pragma unroll
  for (int i = 0; i < 9; ++i) {
    float s, c;
    __sincosf(0.5f * ang[i], &s, &c);
    if (i > 0) {                          // qubit-7 chain: identity after i=0
      bool dead = (cq == 7);
      c = dead ? 1.f : c;
      s = dead ? 0.f : s;
    }
    if ((i & 1) == 0) {                   // RZ
      f32x2 nA = pkfma((f32x2){s, -s}, swap2(A), splat(c) * A);
      f32x2 nB = pkfma((f32x2){-s, s}, swap2(B), splat(c) * B);
      A = nA; B = nB;
    } else {                              // RY
      f32x2 nA = pkfma(splat(-s), B, splat(c) * A);
      f32x2 nB = pkfma(splat(c), B, splat(s) * A);
      A = nA; B = nB;
    }
  }

  // publish chain results: (A,B) per (element, qubit); 256 B per wave
  __shared__ f32x4 ldsAB[4][16];
  const int wvid = (threadIdx.x >> 6) & 3;
  if (lane < 16) ldsAB[wvid][lane] = (f32x4){A.x, A.y, B.x, B.y};
  __builtin_amdgcn_wave_barrier();        // same-wave DS ordering fence

  // ---- build product-state amplitudes (my half's element) ----
  const int half = lane >> 5;
  const int base = half * 8;
  const f32x2* b2 = (const f32x2*)&ldsAB[wvid][0];  // entry 2*k = A_k, 2*k+1 = B_k
  f32x2 P = b2[(base + 0) * 2 + ((lane >> 4) & 1)];
#pragma unroll
  for (int q = 1; q <= 4; ++q)
    P = cmul(P, b2[(base + q) * 2 + ((lane >> (4 - q)) & 1)]);
  f32x4 F5 = ldsAB[wvid][base + 5];
  f32x4 F6 = ldsAB[wvid][base + 6];
  f32x4 F7 = ldsAB[wvid][base + 7];
  f32x2 A5 = {F5.x, F5.y}, B5 = {F5.z, F5.w};
  f32x2 A6 = {F6.x, F6.y}, B6 = {F6.z, F6.w};
  f32x2 A7 = {F7.x, F7.y}, B7 = {F7.z, F7.w};
  f32x2 amp[8];
  {
    f32x2 t0 = cmul(P, A5), t1 = cmul(P, B5);
    f32x2 u00 = cmul(t0, A6), u01 = cmul(t0, B6);
    f32x2 u10 = cmul(t1, A6), u11 = cmul(t1, B6);
    amp[0] = cmul(u00, A7); amp[1] = cmul(u00, B7);
    amp[2] = cmul(u01, A7); amp[3] = cmul(u01, B7);
    amp[4] = cmul(u10, A7); amp[5] = cmul(u10, B7);
    amp[6] = cmul(u11, A7); amp[7] = cmul(u11, B7);
  }

  // ---- entangling: layer 0 = CRX, layer 1 = CRY; ctrl=q_i, tgt=q_{i+1} ----
#pragma unroll
  for (int l = 0; l < 2; ++l) {
    const bool isCRX = (l == 0);
#define CS(G, CBIT) \
    const float cg = rdlane(cw, G), sg = rdlane(sw, G); \
    const bool act = (lane >> (CBIT)) & 1; \
    const float c1 = act ? cg : 1.f, s1 = act ? sg : 0.f;
    { CS(l * 8 + 0, 4)                    // ctrl q0(b4) -> tgt q1(b3): DPP ror8
      if (isCRX) gate_lane<8, true, 0, 1>(amp, lane, c1, s1);
      else       gate_lane<8, false, 0, 1>(amp, lane, c1, s1); }
    { CS(l * 8 + 1, 3)                    // ctrl q1(b3) -> tgt q2(b2): swizzle xor4
      if (isCRX) gate_lane<4, true, 0, 1>(amp, lane, c1, s1);
      else       gate_lane<4, false, 0, 1>(amp, lane, c1, s1); }
    { CS(l * 8 + 2, 2)                    // ctrl q2(b2) -> tgt q3(b1): DPP quad
      if (isCRX) gate_lane<2, true, 0, 1>(amp, lane, c1, s1);
      else       gate_lane<2, false, 0, 1>(amp, lane, c1, s1); }
    { CS(l * 8 + 3, 1)                    // ctrl q3(b1) -> tgt q4(b0): DPP quad
      if (isCRX) gate_lane<1, true, 0, 1>(amp, lane, c1, s1);
      else       gate_lane<1, false, 0, 1>(amp, lane, c1, s1); }
    { CS(l * 8 + 4, 0)                    // ctrl q4(b0) -> tgt q5(r2): pairs (r,r+4)
#pragma unroll
      for (int r = 0; r < 4; ++r) {
        if (isCRX) gate_pair<true>(amp[r], amp[r + 4], c1, s1);
        else       gate_pair<false>(amp[r], amp[r + 4], c1, s1);
      } }
    {                                     // ctrl q5(r2) -> tgt q6(r1): r in {4..7}
      const float cg = rdlane(cw, l * 8 + 5), sg = rdlane(sw, l * 8 + 5);
      if (isCRX) { gate_pair<true>(amp[4], amp[6], cg, sg);
                   gate_pair<true>(amp[5], amp[7], cg, sg); }
      else       { gate_pair<false>(amp[4], amp[6], cg, sg);
                   gate_pair<false>(amp[5], amp[7], cg, sg); }
    }
    {                                     // ctrl q6(r1) -> tgt q7(r0): r in {2,3,6,7}
      const float cg = rdlane(cw, l * 8 + 6), sg = rdlane(sw, l * 8 + 6);
      if (isCRX) { gate_pair<true>(amp[2], amp[3], cg, sg);
                   gate_pair<true>(amp[6], amp[7], cg, sg); }
      else       { gate_pair<false>(amp[2], amp[3], cg, sg);
                   gate_pair<false>(amp[6], amp[7], cg, sg); }
    }
    {                                     // ctrl q7(r0) -> tgt q0(b4): odd r, swizzle xor16
      const float cg = rdlane(cw, l * 8 + 7), sg = rdlane(sw, l * 8 + 7);
      if (isCRX) gate_lane<16, true, 1, 2>(amp, lane, cg, sg);
      else       gate_lane<16, false, 1, 2>(amp, lane, cg, sg);
    }
#undef CS
  }

  // ---- measurement ----
  float p[8];
#pragma unroll
  for (int r = 0; r < 8; ++r) p[r] = fmaf(amp[r].x, amp[r].x, amp[r].y * amp[r].y);
  float s01 = p[0] + p[1], s23 = p[2] + p[3], s45 = p[4] + p[5], s67 = p[6] + p[7];
  float sL = s01 + s23, sH = s45 + s67;
  float wv = sL + sH;                     // WHT input -> qubits 0..4 (lane bits)
  f32x2 D = {sL - sH,                     // q5 (r bit2)
             (s01 + s45) - (s23 + s67)};  // q6 (r bit1)
  float d7 = (p[0] - p[1]) + (p[2] - p[3]) + (p[4] - p[5]) + (p[6] - p[7]); // q7

#define STAGE(K, M)                                   \
  {                                                   \
    float pp = xorl<M>(wv);                           \
    wv = pp + (((lane >> K) & 1) ? -wv : wv);         \
    f32x2 pd;                                         \
    pd.x = xorl<M>(D.x);                              \
    pd.y = xorl<M>(D.y);                              \
    D = D + pd;                                       \
    d7 += xorl<M>(d7);                                \
  }
  STAGE(0, 1) STAGE(1, 2) STAGE(2, 4) STAGE(3, 8) STAGE(4, 16)
#undef STAGE

  // ---- gather & store: each half writes its element's 8 outputs ----
  const int lpos = lane & 31;
  const int srcl = (lane & 32) + (16 >> lpos);   // q0..q4 sit in WHT lanes 16,8,4,2,1
  float g = __shfl(wv, srcl, 64);
  float val = (lpos == 5) ? D.x : (lpos == 6) ? D.y : (lpos == 7) ? d7 : g;
  const int brow = b0 + half;
  if (lpos < 8 && brow < bs) out[(size_t)brow * 8 + lpos] = val;
}

extern "C" void kernel_launch(void* const* d_in, const int* in_sizes, int n_in,
                              void* d_out, int out_size, void* d_ws, size_t ws_size,
                              hipStream_t stream) {
  const float* X = (const float*)d_in[0];   // (bs, 64) float32
  const float* W = (const float*)d_in[1];   // (2, 16) float32
  float* out = (float*)d_out;               // (bs, 8) float32
  int bs = in_sizes[0] / 64;
  int waves = (bs + 1) / 2;                 // 2 elements per wave
  const int waves_per_block = 4;
  const int threads = waves_per_block * 64;
  int blocks = (waves + waves_per_block - 1) / waves_per_block;
  hipLaunchKernelGGL(qsim_kernel, dim3(blocks), dim3(threads), 0, stream, X, W, out, bs);
}